// Round 1
// baseline (21061.432 us; speedup 1.0000x reference)
//
#include <hip/hip_runtime.h>
#include <hip/hip_fp16.h>

#define TT   512
#define BB   128
#define HH   1024
#define K4   4096   // 4*H
#define KK   2048   // concat K = IN + H
#define NWG  256
#define NSLOT (TT + 1)

typedef _Float16 half8  __attribute__((ext_vector_type(8)));
typedef _Float16 half4v __attribute__((ext_vector_type(4)));
typedef float    f32x4  __attribute__((ext_vector_type(4)));

__device__ __forceinline__ float sig_f(float v) { return 1.f / (1.f + __expf(-v)); }
// NaN-free tanh: saturates gracefully at +-1 for large |v|
__device__ __forceinline__ float tanh_f(float v) {
    float e = __expf(2.f * v);
    return 1.f - 2.f / (e + 1.f);
}

// x[b][t][k] fp32 -> xc[t][b][k] fp16
__global__ void cast_x_kernel(const float* __restrict__ x, _Float16* __restrict__ xc) {
    const long n4 = (long)BB * TT * HH / 4;  // float4 count
    const long stride = (long)gridDim.x * blockDim.x;
    for (long i = (long)blockIdx.x * blockDim.x + threadIdx.x; i < n4; i += stride) {
        long row = i >> 8;      // 256 float4 per row of 1024
        int  q   = (int)(i & 255);
        int  b   = (int)(row >> 9);    // row = b*512 + t
        int  t   = (int)(row & 511);
        const float4 v = ((const float4*)x)[i];
        half4v h;
        h[0] = (_Float16)v.x; h[1] = (_Float16)v.y;
        h[2] = (_Float16)v.z; h[3] = (_Float16)v.w;
        ((half4v*)xc)[((long)(t * BB + b) << 8) + q] = h;
    }
}

// zero barrier counters + initial h buffers (parity-1 buffers hold h(-1)=0)
__global__ void init_ws(int* __restrict__ cnt, _Float16* __restrict__ h0b1,
                        _Float16* __restrict__ h1b1) {
    int i = blockIdx.x * blockDim.x + threadIdx.x;
    int stride = gridDim.x * blockDim.x;
    if (i < 1024) cnt[i] = 0;
    for (int j = i; j < BB * HH; j += stride) {
        h0b1[j] = (_Float16)0.f;
        h1b1[j] = (_Float16)0.f;
    }
}

// Persistent 2-layer recurrence. 256 WGs: wg 0..127 = layer0, 128..255 = layer1.
// Each WG owns 8 h-columns (32 gate columns: i/f/g/o strided by 1024), weight
// slice [2048 x 32] fp16 LDS-resident (pre-swizzled into MFMA B-fragment order).
__global__ __launch_bounds__(512, 1) void lstm_main(
    const float* __restrict__ x, const _Float16* __restrict__ xc, int useXC,
    const float* __restrict__ Wx, const float* __restrict__ bx,
    const float* __restrict__ Wh, const float* __restrict__ bh,
    _Float16* __restrict__ h0, _Float16* __restrict__ h1,
    int* __restrict__ cnt)
{
    // LDS: 128KB weights + 16.9KB gate scratch + bias = ~145KB (<=160KB/CU)
    __shared__ _Float16 wlds[KK * 32];
    __shared__ float gates[BB][33];
    __shared__ float bias_s[32];

    const int tid   = threadIdx.x;
    const int wg    = blockIdx.x;
    const int layer = wg >> 7;
    const int wg8   = (wg & 127) * 8;

    // ---- one-time: fill weight slice into LDS, swizzled so each lane's
    // B-fragment (8 consecutive k for one column) is a contiguous 16B run:
    // idx(k,c) = (k>>3)*256 + c*8 + (k&7)
    const float* WxL = Wx + (long)layer * K4 * HH;
    const float* WhL = Wh + (long)layer * K4 * HH;
    for (int e = tid; e < KK * 32; e += 512) {
        int c = e >> 11;          // 0..31  (2048 k per column)
        int k = e & (KK - 1);
        int g = wg8 + (c & 7) + 1024 * (c >> 3);
        float v = (k < HH) ? WxL[(long)g * HH + k] : WhL[(long)g * HH + (k - HH)];
        wlds[((k >> 3) << 8) + (c << 3) + (k & 7)] = (_Float16)v;
    }
    if (tid < 32) {
        int g = wg8 + (tid & 7) + 1024 * (tid >> 3);
        bias_s[tid] = bx[layer * K4 + g] + bh[layer * K4 + g];
    }
    __syncthreads();

    const int lane = tid & 63;
    const int wv   = tid >> 6;      // wave 0..7 -> rows [16*wv, 16*wv+16)
    const int m    = lane & 15;     // A row / B col / C col within 16x16 tile
    const int q    = lane >> 4;     // quad: k-offset q*8 in A/B, row-offset q*4 in C
    const int arow = wv * 16 + m;

    for (int s = 0; s < NSLOT; ++s) {
        const bool active = (layer == 0) ? (s < TT) : (s >= 1);
        if (active) {
            const _Float16* A0h = nullptr;   // K[0,1024) source (fp16)
            const float*    A0f = nullptr;   // K[0,1024) source (fp32 fallback)
            const _Float16* A1h;             // K[1024,2048) source
            _Float16*       outp;
            if (layer == 0) {
                if (useXC) A0h = xc + (long)s * BB * HH;
                else       A0f = x + (long)s * HH;      // + b*(T*H) per row
                A1h  = h0 + ((s + 1) & 1) * (BB * HH);  // h0(s-1)
                outp = h0 + (s & 1) * (BB * HH);        // h0(s)
            } else {
                A0h  = h0 + ((s + 1) & 1) * (BB * HH);  // h0(s-1)
                A1h  = h1 + (s & 1) * (BB * HH);        // h1(s-2)
                outp = h1 + ((s + 1) & 1) * (BB * HH);  // h1(s-1)
            }

            f32x4 acc0 = {0.f, 0.f, 0.f, 0.f};
            f32x4 acc1 = {0.f, 0.f, 0.f, 0.f};

            // ---- K phase 1: k in [0,1024)
            if (A0h) {
                const _Float16* ap = A0h + (long)arow * HH + q * 8;
                #pragma unroll 8
                for (int kk = 0; kk < HH; kk += 32) {
                    half8 af = *(const half8*)(ap + kk);
                    int kb = ((kk >> 3) + q) * 256 + m * 8;
                    half8 b0 = *(const half8*)&wlds[kb];
                    half8 b1 = *(const half8*)&wlds[kb + 128];
                    acc0 = __builtin_amdgcn_mfma_f32_16x16x32_f16(af, b0, acc0, 0, 0, 0);
                    acc1 = __builtin_amdgcn_mfma_f32_16x16x32_f16(af, b1, acc1, 0, 0, 0);
                }
            } else {
                const float* ap = A0f + (long)arow * (TT * HH) + q * 8;
                #pragma unroll 8
                for (int kk = 0; kk < HH; kk += 32) {
                    float4 f0 = *(const float4*)(ap + kk);
                    float4 f1 = *(const float4*)(ap + kk + 4);
                    half8 af;
                    af[0] = (_Float16)f0.x; af[1] = (_Float16)f0.y;
                    af[2] = (_Float16)f0.z; af[3] = (_Float16)f0.w;
                    af[4] = (_Float16)f1.x; af[5] = (_Float16)f1.y;
                    af[6] = (_Float16)f1.z; af[7] = (_Float16)f1.w;
                    int kb = ((kk >> 3) + q) * 256 + m * 8;
                    half8 b0 = *(const half8*)&wlds[kb];
                    half8 b1 = *(const half8*)&wlds[kb + 128];
                    acc0 = __builtin_amdgcn_mfma_f32_16x16x32_f16(af, b0, acc0, 0, 0, 0);
                    acc1 = __builtin_amdgcn_mfma_f32_16x16x32_f16(af, b1, acc1, 0, 0, 0);
                }
            }
            // ---- K phase 2: k in [1024,2048)
            {
                const _Float16* ap = A1h + (long)arow * HH + q * 8;
                #pragma unroll 8
                for (int kk = 0; kk < HH; kk += 32) {
                    half8 af = *(const half8*)(ap + kk);
                    int kb = (((kk + HH) >> 3) + q) * 256 + m * 8;
                    half8 b0 = *(const half8*)&wlds[kb];
                    half8 b1 = *(const half8*)&wlds[kb + 128];
                    acc0 = __builtin_amdgcn_mfma_f32_16x16x32_f16(af, b0, acc0, 0, 0, 0);
                    acc1 = __builtin_amdgcn_mfma_f32_16x16x32_f16(af, b1, acc1, 0, 0, 0);
                }
            }

            // C layout: col = lane&15, row = (lane>>4)*4 + reg  (HW-verified)
            #pragma unroll
            for (int r = 0; r < 4; ++r) {
                gates[wv * 16 + q * 4 + r][m]      = acc0[r];
                gates[wv * 16 + q * 4 + r][16 + m] = acc1[r];
            }
            __syncthreads();

            // activation: 128 rows x 8 h-cols, 2 per thread
            for (int e = tid; e < BB * 8; e += 512) {
                int row = e >> 3, j = e & 7;
                float gi = gates[row][j]      + bias_s[j];
                float gf = gates[row][8 + j]  + bias_s[8 + j];
                float gg = gates[row][16 + j] + bias_s[16 + j];
                float go = gates[row][24 + j] + bias_s[24 + j];
                float cy = tanh_f(gg) * (sig_f(gf) + sig_f(gi));
                float hy = tanh_f(cy) * sig_f(go);
                outp[(long)row * HH + wg8 + j] = (_Float16)hy;
            }
        }

        // ---- device-wide slot barrier (per-slot counter, agent-scope fences)
        __syncthreads();
        if (tid == 0) {
            __threadfence();  // release our h writes
            __hip_atomic_fetch_add(&cnt[s], 1, __ATOMIC_RELEASE, __HIP_MEMORY_SCOPE_AGENT);
            while (__hip_atomic_load(&cnt[s], __ATOMIC_ACQUIRE, __HIP_MEMORY_SCOPE_AGENT) < NWG)
                __builtin_amdgcn_s_sleep(2);
            __threadfence();  // acquire everyone else's h writes
        }
        __syncthreads();
    }
}

// out[b][o] = sum_k h1_last[b][k] * Wout[o][k] + bout[o]   (fp32)
__global__ void out_kernel(const _Float16* __restrict__ hlast,
                           const float* __restrict__ Wout,
                           const float* __restrict__ bout,
                           float* __restrict__ out) {
    int b = blockIdx.x, o = blockIdx.y;
    int lane = threadIdx.x;
    float sum = 0.f;
    for (int k = lane; k < HH; k += 64)
        sum += (float)hlast[(long)b * HH + k] * Wout[(long)o * HH + k];
    #pragma unroll
    for (int off = 32; off; off >>= 1) sum += __shfl_down(sum, off, 64);
    if (lane == 0) out[b * 20 + o] = sum + bout[o];
}

extern "C" void kernel_launch(void* const* d_in, const int* in_sizes, int n_in,
                              void* d_out, int out_size, void* d_ws, size_t ws_size,
                              hipStream_t stream) {
    const float* x    = (const float*)d_in[0];
    const float* Wx   = (const float*)d_in[1];
    const float* bx   = (const float*)d_in[2];
    const float* Wh   = (const float*)d_in[3];
    const float* bh   = (const float*)d_in[4];
    const float* Wout = (const float*)d_in[5];
    const float* bout = (const float*)d_in[6];
    float* out = (float*)d_out;

    char* ws = (char*)d_ws;
    int*      cnt = (int*)ws;                                  // 4KB
    _Float16* h0  = (_Float16*)(ws + 4096);                    // 2 x 256KB
    _Float16* h1  = (_Float16*)(ws + 4096 + 524288);           // 2 x 256KB
    _Float16* xc  = (_Float16*)(ws + 4096 + 1048576);          // 128MB
    size_t need_xc = 4096 + 1048576 + (size_t)TT * BB * HH * 2;
    int useXC = (ws_size >= need_xc) ? 1 : 0;

    hipLaunchKernelGGL(init_ws, dim3(64), dim3(256), 0, stream,
                       cnt, h0 + BB * HH, h1 + BB * HH);
    if (useXC)
        hipLaunchKernelGGL(cast_x_kernel, dim3(8192), dim3(256), 0, stream, x, xc);
    hipLaunchKernelGGL(lstm_main, dim3(NWG), dim3(512), 0, stream,
                       x, xc, useXC, Wx, bx, Wh, bh, h0, h1, cnt);
    // h1(T-1) lives in parity buffer (T-1)&1 = 1
    hipLaunchKernelGGL(out_kernel, dim3(BB, 20), dim3(64), 0, stream,
                       h1 + BB * HH, Wout, bout, out);
}

// Round 2
// 17774.942 us; speedup vs baseline: 1.1849x; 1.1849x over previous
//
#include <hip/hip_runtime.h>
#include <hip/hip_fp16.h>

#define TT   512
#define BB   128
#define HH   1024
#define K4   4096   // 4*H
#define KK   2048   // concat K = IN + H
#define NWG  256
#define NSLOT (TT + 1)
#define FSTRIDE 32  // flag stride in ints (128B lines)

typedef _Float16 half8  __attribute__((ext_vector_type(8)));
typedef _Float16 half4v __attribute__((ext_vector_type(4)));
typedef float    f32x4  __attribute__((ext_vector_type(4)));

__device__ __forceinline__ float sig_f(float v) { return 1.f / (1.f + __expf(-v)); }
__device__ __forceinline__ float tanh_f(float v) {
    float e = __expf(2.f * v);
    return 1.f - 2.f / (e + 1.f);
}

// x[b][t][k] fp32 -> xc[t][b][k] fp16
__global__ void cast_x_kernel(const float* __restrict__ x, _Float16* __restrict__ xc) {
    const long n4 = (long)BB * TT * HH / 4;
    const long stride = (long)gridDim.x * blockDim.x;
    for (long i = (long)blockIdx.x * blockDim.x + threadIdx.x; i < n4; i += stride) {
        long row = i >> 8;
        int  qq  = (int)(i & 255);
        int  b   = (int)(row >> 9);
        int  t   = (int)(row & 511);
        const float4 v = ((const float4*)x)[i];
        half4v h;
        h[0] = (_Float16)v.x; h[1] = (_Float16)v.y;
        h[2] = (_Float16)v.z; h[3] = (_Float16)v.w;
        ((half4v*)xc)[((long)(t * BB + b) << 8) + qq] = h;
    }
}

// zero flags + initial h buffers (parity-1 buffers hold h(-1)=0)
__global__ void init_ws(int* __restrict__ flags, _Float16* __restrict__ h0b1,
                        _Float16* __restrict__ h1b1) {
    int i = blockIdx.x * blockDim.x + threadIdx.x;
    int stride = gridDim.x * blockDim.x;
    if (i < NWG * FSTRIDE) flags[i] = 0;
    for (int j = i; j < BB * HH; j += stride) {
        h0b1[j] = (_Float16)0.f;
        h1b1[j] = (_Float16)0.f;
    }
}

// Persistent 2-layer recurrence. 256 WGs: wg 0..127 = layer0, 128..255 = layer1.
// Each WG owns 8 h-columns (32 gate columns), weight slice [2048 x 32] fp16
// LDS-resident, XOR-swizzled into MFMA B-fragment order.
__global__ __launch_bounds__(512, 1) void lstm_main(
    const float* __restrict__ x, const _Float16* __restrict__ xc, int useXC,
    const float* __restrict__ Wx, const float* __restrict__ bx,
    const float* __restrict__ Wh, const float* __restrict__ bh,
    _Float16* __restrict__ h0, _Float16* __restrict__ h1,
    int* __restrict__ flags)
{
    __shared__ _Float16 wlds[KK * 32];     // 128 KB
    __shared__ float gates[BB][33];        // 16.9 KB
    __shared__ float bias_s[32];

    const int tid   = threadIdx.x;
    const int wg    = blockIdx.x;
    const int layer = wg >> 7;
    const int wg8   = (wg & 127) * 8;

    // One-time weight fill. Swizzle: element (k, c) stored at
    //   row = k>>3; chunk = (c&24) | ((c^row)&7); elem = row*256 + chunk*8 + (k&7)
    // so quads q=0..3 (consecutive rows) read distinct bank-quads.
    const float* WxL = Wx + (long)layer * K4 * HH;
    const float* WhL = Wh + (long)layer * K4 * HH;
    for (int e = tid; e < KK * 32; e += 512) {
        int c = e >> 11;
        int k = e & (KK - 1);
        int g = wg8 + (c & 7) + 1024 * (c >> 3);
        float v = (k < HH) ? WxL[(long)g * HH + k] : WhL[(long)g * HH + (k - HH)];
        int row = k >> 3;
        int cs  = (c & 24) | ((c ^ row) & 7);
        wlds[row * 256 + cs * 8 + (k & 7)] = (_Float16)v;
    }
    if (tid < 32) {
        int g = wg8 + (tid & 7) + 1024 * (tid >> 3);
        bias_s[tid] = bx[layer * K4 + g] + bh[layer * K4 + g];
    }
    __syncthreads();

    const int lane = tid & 63;
    const int wv   = tid >> 6;      // wave 0..7 -> A rows [16*wv, 16*wv+16)
    const int m    = lane & 15;
    const int q    = lane >> 4;
    const int arow = wv * 16 + m;

    f32x4 acc0 = {0.f, 0.f, 0.f, 0.f};
    f32x4 acc1 = {0.f, 0.f, 0.f, 0.f};

    // B-fragment read (swizzled). row = k-block index 0..255.
    auto bread = [&](int row, half8& b0, half8& b1) {
        int base = row * 256 + (((m & 8) | ((m ^ row) & 7)) << 3);
        b0 = *(const half8*)&wlds[base];
        b1 = *(const half8*)&wlds[base + 128];
    };
    // GEMM over 1024 K from an fp16 [128][1024] panel; kbOff = k-block base (0 or 128)
    auto gemm_h16 = [&](const _Float16* A, int kbOff) {
        const _Float16* ap = A + (long)arow * HH + q * 8;
        #pragma unroll 8
        for (int kk = 0; kk < HH; kk += 32) {
            half8 af = *(const half8*)(ap + kk);
            int row = (kk >> 3) + kbOff + q;
            half8 b0, b1; bread(row, b0, b1);
            acc0 = __builtin_amdgcn_mfma_f32_16x16x32_f16(af, b0, acc0, 0, 0, 0);
            acc1 = __builtin_amdgcn_mfma_f32_16x16x32_f16(af, b1, acc1, 0, 0, 0);
        }
    };
    // fp32 fallback for x (row stride T*H), k-blocks 0..127
    auto gemm_f32 = [&](const float* ap0) {
        const float* ap = ap0 + (long)arow * (TT * HH) + q * 8;
        #pragma unroll 4
        for (int kk = 0; kk < HH; kk += 32) {
            float4 f0 = *(const float4*)(ap + kk);
            float4 f1 = *(const float4*)(ap + kk + 4);
            half8 af;
            af[0] = (_Float16)f0.x; af[1] = (_Float16)f0.y;
            af[2] = (_Float16)f0.z; af[3] = (_Float16)f0.w;
            af[4] = (_Float16)f1.x; af[5] = (_Float16)f1.y;
            af[6] = (_Float16)f1.z; af[7] = (_Float16)f1.w;
            int row = (kk >> 3) + q;
            half8 b0, b1; bread(row, b0, b1);
            acc0 = __builtin_amdgcn_mfma_f32_16x16x32_f16(af, b0, acc0, 0, 0, 0);
            acc1 = __builtin_amdgcn_mfma_f32_16x16x32_f16(af, b1, acc1, 0, 0, 0);
        }
    };

    // Prologue: layer0 precomputes the x-contribution for t=0 (no barrier needed)
    if (layer == 0) {
        if (useXC) gemm_h16(xc, 0);
        else       gemm_f32(x);
    }

    int* myflag = flags + wg * FSTRIDE;

    for (int s = 0; s < NSLOT; ++s) {
        // ---- wait: everyone finished slot s-1 (distributed per-flag polling)
        if (s) {
            if (tid < NWG) {
                const int* fp = flags + tid * FSTRIDE;
                while (__hip_atomic_load(fp, __ATOMIC_RELAXED, __HIP_MEMORY_SCOPE_AGENT) < s)
                    __builtin_amdgcn_s_sleep(1);
                (void)__hip_atomic_load(fp, __ATOMIC_ACQUIRE, __HIP_MEMORY_SCOPE_AGENT);
            }
            __syncthreads();
        }

        const bool active = (layer == 0) ? (s < TT) : (s >= 1);
        if (active) {
            _Float16* outp;
            if (layer == 0) {
                // phase1 (x) already in acc from precompute; add h0(s-1)
                gemm_h16(h0 + ((s + 1) & 1) * (BB * HH), 128);
                outp = h0 + (s & 1) * (BB * HH);
            } else {
                acc0 = (f32x4){0.f, 0.f, 0.f, 0.f};
                acc1 = (f32x4){0.f, 0.f, 0.f, 0.f};
                gemm_h16(h0 + ((s + 1) & 1) * (BB * HH), 0);    // h0(s-1)
                gemm_h16(h1 + (s & 1) * (BB * HH), 128);        // h1(s-2)
                outp = h1 + ((s + 1) & 1) * (BB * HH);          // h1(s-1)
            }

            // C layout: col = lane&15, row = (lane>>4)*4 + reg  (HW-verified)
            #pragma unroll
            for (int r = 0; r < 4; ++r) {
                gates[wv * 16 + q * 4 + r][m]      = acc0[r];
                gates[wv * 16 + q * 4 + r][16 + m] = acc1[r];
            }
            __syncthreads();

            for (int e = tid; e < BB * 8; e += 512) {
                int row = e >> 3, j = e & 7;
                float gi = gates[row][j]      + bias_s[j];
                float gf = gates[row][8 + j]  + bias_s[8 + j];
                float gg = gates[row][16 + j] + bias_s[16 + j];
                float go = gates[row][24 + j] + bias_s[24 + j];
                float cy = tanh_f(gg) * (sig_f(gf) + sig_f(gi));
                float hy = tanh_f(cy) * sig_f(go);
                outp[(long)row * HH + wg8 + j] = (_Float16)hy;
            }
            __syncthreads();
        }

        // ---- arrive: uncontended release store to own flag line
        if (tid == 0) {
            __threadfence();
            __hip_atomic_store(myflag, s + 1, __ATOMIC_RELEASE, __HIP_MEMORY_SCOPE_AGENT);
        }

        // ---- layer0: precompute next step's x-GEMM while others catch up
        if (layer == 0 && (s + 1) < TT) {
            acc0 = (f32x4){0.f, 0.f, 0.f, 0.f};
            acc1 = (f32x4){0.f, 0.f, 0.f, 0.f};
            if (useXC) gemm_h16(xc + (long)(s + 1) * BB * HH, 0);
            else       gemm_f32(x + (long)(s + 1) * HH);
        }
    }
}

// out[b][o] = sum_k h1_last[b][k] * Wout[o][k] + bout[o]   (fp32)
__global__ void out_kernel(const _Float16* __restrict__ hlast,
                           const float* __restrict__ Wout,
                           const float* __restrict__ bout,
                           float* __restrict__ out) {
    int b = blockIdx.x, o = blockIdx.y;
    int lane = threadIdx.x;
    float sum = 0.f;
    for (int k = lane; k < HH; k += 64)
        sum += (float)hlast[(long)b * HH + k] * Wout[(long)o * HH + k];
    #pragma unroll
    for (int off = 32; off; off >>= 1) sum += __shfl_down(sum, off, 64);
    if (lane == 0) out[b * 20 + o] = sum + bout[o];
}

extern "C" void kernel_launch(void* const* d_in, const int* in_sizes, int n_in,
                              void* d_out, int out_size, void* d_ws, size_t ws_size,
                              hipStream_t stream) {
    const float* x    = (const float*)d_in[0];
    const float* Wx   = (const float*)d_in[1];
    const float* bx   = (const float*)d_in[2];
    const float* Wh   = (const float*)d_in[3];
    const float* bh   = (const float*)d_in[4];
    const float* Wout = (const float*)d_in[5];
    const float* bout = (const float*)d_in[6];
    float* out = (float*)d_out;

    char* ws = (char*)d_ws;
    int*      flags = (int*)ws;                                 // 32 KB (256 x 128B)
    _Float16* h0  = (_Float16*)(ws + 32768);                    // 2 x 256KB
    _Float16* h1  = (_Float16*)(ws + 32768 + 524288);           // 2 x 256KB
    _Float16* xc  = (_Float16*)(ws + 32768 + 1048576);          // 128MB
    size_t need_xc = 32768 + 1048576 + (size_t)TT * BB * HH * 2;
    int useXC = (ws_size >= need_xc) ? 1 : 0;

    hipLaunchKernelGGL(init_ws, dim3(64), dim3(256), 0, stream,
                       flags, h0 + BB * HH, h1 + BB * HH);
    if (useXC)
        hipLaunchKernelGGL(cast_x_kernel, dim3(8192), dim3(256), 0, stream, x, xc);
    hipLaunchKernelGGL(lstm_main, dim3(NWG), dim3(512), 0, stream,
                       x, xc, useXC, Wx, bx, Wh, bh, h0, h1, flags);
    // h1(T-1) lives in parity buffer 1
    hipLaunchKernelGGL(out_kernel, dim3(BB, 20), dim3(64), 0, stream,
                       h1 + BB * HH, Wout, bout, out);
}

// Round 3
// 11170.342 us; speedup vs baseline: 1.8855x; 1.5913x over previous
//
#include <hip/hip_runtime.h>
#include <hip/hip_fp16.h>

#define TT   512
#define BB   128
#define HH   1024
#define K4   4096   // 4*H
#define KK   2048   // concat K
#define NWG  256
#define NSLOT (TT + 2)   // layer1 lags 2 slots
#define FSTRIDE 32       // flag stride in ints (128B lines)
#define PANEL 131072     // halves per [128][1024] fragment-layout panel

typedef _Float16 half8  __attribute__((ext_vector_type(8)));
typedef _Float16 half4v __attribute__((ext_vector_type(4)));
typedef float    f32x4  __attribute__((ext_vector_type(4)));

__device__ __forceinline__ float sig_f(float v) { return 1.f / (1.f + __expf(-v)); }
__device__ __forceinline__ float tanh_f(float v) {
    float e = __expf(2.f * v);
    return 1.f - 2.f / (e + 1.f);
}

__device__ __forceinline__ int vload(const int* p) { return *(const volatile int*)p; }
__device__ __forceinline__ void vstore(int* p, int v) { *(volatile int*)p = v; }

// fragment layout offset for a [128][1024] panel:
// lane = ((k>>3)&3)<<4 | (row&15); off = ((row>>4)*32 + (k>>5))*512 + lane*8 + (k&7)

// x[b][t][k] fp32 -> xc[t] panels in MFMA A-fragment layout (fp16)
__global__ void cast_x_kernel(const float* __restrict__ x, _Float16* __restrict__ xc) {
    const long n4 = (long)BB * TT * 256;   // float4 groups
    const long stride = (long)gridDim.x * blockDim.x;
    for (long i = (long)blockIdx.x * blockDim.x + threadIdx.x; i < n4; i += stride) {
        int  kq  = (int)(i & 255);
        long row = i >> 8;
        int  t   = (int)(row & 511);
        int  b   = (int)(row >> 9);
        const float4 v = ((const float4*)x)[i];
        half4v h;
        h[0] = (_Float16)v.x; h[1] = (_Float16)v.y;
        h[2] = (_Float16)v.z; h[3] = (_Float16)v.w;
        int k0  = kq * 4;
        int off = (((b >> 4) * 32 + (k0 >> 5)) << 9)
                + (((((k0 >> 3) & 3) << 4) | (b & 15)) << 3) + (k0 & 7);
        *(half4v*)(xc + (long)t * PANEL + off) = h;
    }
}

// zero flags/gflags + initial h panels (h0 buf2 = h0(-1), h1 parity1 = h1(-1))
__global__ void init_ws(int* __restrict__ flags, _Float16* __restrict__ h0b2,
                        _Float16* __restrict__ h1b1) {
    int i = blockIdx.x * blockDim.x + threadIdx.x;
    int stride = gridDim.x * blockDim.x;
    if (i < (NWG + 16) * FSTRIDE) flags[i] = 0;
    for (int j = i; j < PANEL; j += stride) {
        h0b2[j] = (_Float16)0.f;
        h1b1[j] = (_Float16)0.f;
    }
}

// Persistent 2-layer recurrence, layer1 two slots behind layer0.
// wg 0..127 = layer0 (h-cols wg*8..), wg 128..255 = layer1.
__global__ __launch_bounds__(512, 1) void lstm_main(
    const float* __restrict__ x, const _Float16* __restrict__ xc, int useXC,
    const float* __restrict__ Wx, const float* __restrict__ bx,
    const float* __restrict__ Wh, const float* __restrict__ bh,
    _Float16* __restrict__ h0, _Float16* __restrict__ h1,
    int* __restrict__ flags, int* __restrict__ gflag)
{
    __shared__ _Float16 wlds[KK * 32];     // 128 KB
    __shared__ float gates[BB][33];        // 16.9 KB
    __shared__ float bias_s[32];

    const int tid   = threadIdx.x;
    const int wg    = blockIdx.x;
    const int layer = wg >> 7;
    const int idx   = wg & 127;
    const int wg8   = idx * 8;
    const int cBlk  = idx >> 2;            // frag c-block of this WG's 8 cols
    const int ksub  = idx & 3;             // frag k-sub of this WG's 8 cols
    const bool isLeader = (layer == 1) && (((wg - 128) & 7) == 0);
    const int grp = (wg - 128) >> 3;

    // One-time weight fill (XOR-swizzled B-fragment order, as R2)
    const float* WxL = Wx + (long)layer * K4 * HH;
    const float* WhL = Wh + (long)layer * K4 * HH;
    for (int e = tid; e < KK * 32; e += 512) {
        int c = e >> 11;
        int k = e & (KK - 1);
        int g = wg8 + (c & 7) + 1024 * (c >> 3);
        float v = (k < HH) ? WxL[(long)g * HH + k] : WhL[(long)g * HH + (k - HH)];
        int row = k >> 3;
        int cs  = (c & 24) | ((c ^ row) & 7);
        wlds[row * 256 + cs * 8 + (k & 7)] = (_Float16)v;
    }
    if (tid < 32) {
        int g = wg8 + (tid & 7) + 1024 * (tid >> 3);
        bias_s[tid] = bx[layer * K4 + g] + bh[layer * K4 + g];
    }
    __syncthreads();

    const int lane = tid & 63;
    const int wv   = tid >> 6;
    const int m    = lane & 15;
    const int q    = lane >> 4;
    const int arow = wv * 16 + m;

    f32x4 acc0 = {0.f, 0.f, 0.f, 0.f};
    f32x4 acc1 = {0.f, 0.f, 0.f, 0.f};

    // GEMM over a fragment-layout panel. vol=1 -> L1/L2-bypass (sc0|sc1) loads.
    auto gemm = [&](const _Float16* A, int kb0, int vol) {
        const _Float16* ap = A + (size_t)wv * 16384 + (size_t)lane * 8;
        for (int hb = 0; hb < 2; ++hb) {
            half8 abuf[16];
            if (vol) {
                #pragma unroll
                for (int i = 0; i < 16; ++i) {
                    const volatile unsigned long long* p =
                        (const volatile unsigned long long*)(ap + (hb * 16 + i) * 512);
                    union { unsigned long long u[2]; half8 h; } vv;
                    vv.u[0] = p[0]; vv.u[1] = p[1];
                    abuf[i] = vv.h;
                }
            } else {
                #pragma unroll
                for (int i = 0; i < 16; ++i)
                    abuf[i] = *(const half8*)(ap + (hb * 16 + i) * 512);
            }
            #pragma unroll
            for (int i = 0; i < 16; ++i) {
                int rb = kb0 + (hb * 16 + i) * 4 + q;
                int base = rb * 256 + (((m & 8) | ((m ^ rb) & 7)) << 3);
                half8 b0 = *(const half8*)&wlds[base];
                half8 b1 = *(const half8*)&wlds[base + 128];
                acc0 = __builtin_amdgcn_mfma_f32_16x16x32_f16(abuf[i], b0, acc0, 0, 0, 0);
                acc1 = __builtin_amdgcn_mfma_f32_16x16x32_f16(abuf[i], b1, acc1, 0, 0, 0);
            }
        }
    };
    // fp32 fallback for x (row-major, cached loads), k-blocks 0..127
    auto gemm_f32 = [&](const float* ap0) {
        const float* ap = ap0 + (long)arow * (TT * HH) + q * 8;
        #pragma unroll 4
        for (int kk = 0; kk < HH; kk += 32) {
            float4 f0 = *(const float4*)(ap + kk);
            float4 f1 = *(const float4*)(ap + kk + 4);
            half8 af;
            af[0] = (_Float16)f0.x; af[1] = (_Float16)f0.y;
            af[2] = (_Float16)f0.z; af[3] = (_Float16)f0.w;
            af[4] = (_Float16)f1.x; af[5] = (_Float16)f1.y;
            af[6] = (_Float16)f1.z; af[7] = (_Float16)f1.w;
            int rb = (kk >> 3) + q;
            int base = rb * 256 + (((m & 8) | ((m ^ rb) & 7)) << 3);
            half8 b0 = *(const half8*)&wlds[base];
            half8 b1 = *(const half8*)&wlds[base + 128];
            acc0 = __builtin_amdgcn_mfma_f32_16x16x32_f16(af, b0, acc0, 0, 0, 0);
            acc1 = __builtin_amdgcn_mfma_f32_16x16x32_f16(af, b1, acc1, 0, 0, 0);
        }
    };

    int* myflag = flags + wg * FSTRIDE;

    for (int s = 0; s < NSLOT; ++s) {
        const bool active = (layer == 0) ? (s < TT) : (s >= 2);
        const int p3w = s % 3;              // h0 write buf
        const int p3r1 = (s + 2) % 3;       // h0(s-1) buf
        const int p3r2 = (s + 1) % 3;       // h0(s-2) buf

        // ---- PREFETCH (independent of barrier s-1)
        acc0 = (f32x4){0.f, 0.f, 0.f, 0.f};
        acc1 = (f32x4){0.f, 0.f, 0.f, 0.f};
        if (active) {
            if (layer == 0) {
                if (useXC) gemm(xc + (long)s * PANEL, 0, 0);   // cached: read-only
                else       gemm_f32(x + (long)s * HH);
            } else {
                gemm(h0 + (size_t)p3r2 * PANEL, 0, 1);         // h0(s-2), ready @ barrier s-2
            }
        }

        // ---- WAIT for barrier s-1 (16 group flags)
        if (s) {
            if (tid < 16) {
                const int* gp = gflag + tid * FSTRIDE;
                while (vload(gp) < s) __builtin_amdgcn_s_sleep(4);
            }
            __atomic_signal_fence(__ATOMIC_SEQ_CST);
            __syncthreads();
        }

        // ---- MAIN (dependent GEMM) + activation + h store
        if (active) {
            _Float16* outp;
            if (layer == 0) {
                gemm(h0 + (size_t)p3r1 * PANEL, 128, 1);       // h0(s-1)
                outp = h0 + (size_t)p3w * PANEL;               // h0(s)
            } else {
                gemm(h1 + (size_t)((s + 1) & 1) * PANEL, 128, 1);  // h1(s-3)
                outp = h1 + (size_t)(s & 1) * PANEL;               // h1(s-2)
            }

            #pragma unroll
            for (int r = 0; r < 4; ++r) {
                gates[wv * 16 + q * 4 + r][m]      = acc0[r];
                gates[wv * 16 + q * 4 + r][16 + m] = acc1[r];
            }
            __syncthreads();

            {   // one (row, col-pair) per thread; volatile u32 store (write-through)
                int row = tid >> 2, jp = tid & 3;
                int j0 = jp * 2, j1 = j0 + 1;
                float gi0 = gates[row][j0]      + bias_s[j0];
                float gf0 = gates[row][8 + j0]  + bias_s[8 + j0];
                float gg0 = gates[row][16 + j0] + bias_s[16 + j0];
                float go0 = gates[row][24 + j0] + bias_s[24 + j0];
                float gi1 = gates[row][j1]      + bias_s[j1];
                float gf1 = gates[row][8 + j1]  + bias_s[8 + j1];
                float gg1 = gates[row][16 + j1] + bias_s[16 + j1];
                float go1 = gates[row][24 + j1] + bias_s[24 + j1];
                float hv0 = tanh_f(tanh_f(gg0) * (sig_f(gf0) + sig_f(gi0))) * sig_f(go0);
                float hv1 = tanh_f(tanh_f(gg1) * (sig_f(gf1) + sig_f(gi1))) * sig_f(go1);
                union { _Float16 f[2]; unsigned int u; } pk;
                pk.f[0] = (_Float16)hv0; pk.f[1] = (_Float16)hv1;
                int off = (((row >> 4) * 32 + cBlk) << 9)
                        + (((ksub << 4) | (row & 15)) << 3) + j0;
                *(volatile unsigned int*)(outp + off) = pk.u;
            }
        }

        // ---- ARRIVE: __syncthreads drains all waves' vmcnt (stores acked at LLC)
        __syncthreads();
        if (tid == 0) {
            __atomic_signal_fence(__ATOMIC_SEQ_CST);
            vstore(myflag, s + 1);
        }
        // ---- leaders aggregate their 16 members -> group flag
        if (isLeader) {
            if (tid < 16) {
                const int* fp = flags + (grp * 16 + tid) * FSTRIDE;
                while (vload(fp) < s + 1) __builtin_amdgcn_s_sleep(2);
            }
            if (tid == 0) {
                __atomic_signal_fence(__ATOMIC_SEQ_CST);
                vstore(gflag + grp * FSTRIDE, s + 1);
            }
        }
    }
}

// out[b][o] = sum_k h1_last[b][k] * Wout[o][k] + bout[o]; h1_last in frag layout
__global__ void out_kernel(const _Float16* __restrict__ hlast,
                           const float* __restrict__ Wout,
                           const float* __restrict__ bout,
                           float* __restrict__ out) {
    int b = blockIdx.x, o = blockIdx.y;
    int lane = threadIdx.x;
    float sum = 0.f;
    for (int k = lane; k < HH; k += 64) {
        int off = (((b >> 4) * 32 + (k >> 5)) << 9)
                + (((((k >> 3) & 3) << 4) | (b & 15)) << 3) + (k & 7);
        sum += (float)hlast[off] * Wout[(long)o * HH + k];
    }
    #pragma unroll
    for (int offz = 32; offz; offz >>= 1) sum += __shfl_down(sum, offz, 64);
    if (lane == 0) out[b * 20 + o] = sum + bout[o];
}

extern "C" void kernel_launch(void* const* d_in, const int* in_sizes, int n_in,
                              void* d_out, int out_size, void* d_ws, size_t ws_size,
                              hipStream_t stream) {
    const float* x    = (const float*)d_in[0];
    const float* Wx   = (const float*)d_in[1];
    const float* bx   = (const float*)d_in[2];
    const float* Wh   = (const float*)d_in[3];
    const float* bh   = (const float*)d_in[4];
    const float* Wout = (const float*)d_in[5];
    const float* bout = (const float*)d_in[6];
    float* out = (float*)d_out;

    char* ws = (char*)d_ws;
    int*      flags = (int*)ws;                          // 256 x 128B = 32 KB
    int*      gflag = (int*)(ws + 32768);                // 16 x 128B = 2 KB
    _Float16* h0  = (_Float16*)(ws + 40960);             // 3 x 256 KB
    _Float16* h1  = (_Float16*)(ws + 40960 + 786432);    // 2 x 256 KB
    _Float16* xc  = (_Float16*)(ws + 40960 + 1310720);   // 128 MB
    size_t need_xc = 40960 + 1310720 + (size_t)TT * PANEL * 2;
    int useXC = (ws_size >= need_xc) ? 1 : 0;

    hipLaunchKernelGGL(init_ws, dim3(64), dim3(256), 0, stream,
                       flags, h0 + 2 * (size_t)PANEL, h1 + PANEL);
    if (useXC)
        hipLaunchKernelGGL(cast_x_kernel, dim3(8192), dim3(256), 0, stream, x, xc);
    hipLaunchKernelGGL(lstm_main, dim3(NWG), dim3(512), 0, stream,
                       x, xc, useXC, Wx, bx, Wh, bh, h0, h1, flags, gflag);
    // h1(T-1) written at slot T+1 into parity (T+1)&1 = 1
    hipLaunchKernelGGL(out_kernel, dim3(BB, 20), dim3(64), 0, stream,
                       h1 + PANEL, Wout, bout, out);
}